// Round 8
// baseline (1381.045 us; speedup 1.0000x reference)
//
#include <hip/hip_runtime.h>
#include <hip/hip_bf16.h>

// ---------------------------------------------------------------------------
// GNN pretrain forward: h=relu(x@Wl+bl); 5x [gather-agg -> fusedMLP -> BN]
// R12: fused MLP pass1 with SWAPPED MFMA operands: mfma(W1f, af) instead of
// mfma(af, W1f). Output fragment becomes row-major per thread:
//   hid[row = mt*16+l16][cols = wid*16+quad*4 .. +4]
// so the hid write is 8x bf16x4 vector stores per chunk (was 32 scalar bf16
// stores -> 10.8M bank-conflict cycles = 12% of runtime in R11).
// Everything else (M=128 tile, 512 thr, 96KB LDS, prefetch, gather x4 unroll,
// 8-way replicated BN atomics) unchanged from R11 (147us, total 1359).
// ---------------------------------------------------------------------------

typedef __bf16 bf16x8 __attribute__((ext_vector_type(8)));
typedef __bf16 bf16x4 __attribute__((ext_vector_type(4)));
typedef float f32x4 __attribute__((ext_vector_type(4)));

#define LDSTRIDE 40  // gemm0 LDS pad

// ------------------- gemm0 (fp32 in, fp32 out, relu) -----------------------
// 128x128 block tile, 4 waves (2x2), each wave 64x64 = 4x4 MFMA tiles.
__global__ __launch_bounds__(256, 2)
void gemm0_kernel(const float* __restrict__ Av, const __bf16* __restrict__ BT,
                  const float* __restrict__ bias, float* __restrict__ Cv,
                  int M, int K, int Nc)
{
    __shared__ __bf16 As[128 * LDSTRIDE];
    __shared__ __bf16 Bs[128 * LDSTRIDE];

    const int tid  = threadIdx.x;
    const int wave = tid >> 6;
    const int lane = tid & 63;
    const int quad = lane >> 4;
    const int l16  = lane & 15;
    const int wm   = wave >> 1;
    const int wn   = wave & 1;

    const int col0 = blockIdx.x * 128;
    const int row0 = blockIdx.y * 128;

    f32x4 acc[4][4];
#pragma unroll
    for (int mt = 0; mt < 4; ++mt)
#pragma unroll
        for (int nt = 0; nt < 4; ++nt) acc[mt][nt] = (f32x4){0.f, 0.f, 0.f, 0.f};

    const int srow = tid >> 1;
    const int scol = (tid & 1) * 16;
    const int a_row = row0 + srow;
    const bool a_ok = (a_row < M);
    const __bf16* Bp = BT + (size_t)(col0 + srow) * K + scol;

    for (int k0 = 0; k0 < K; k0 += 32) {
        bf16x8 a0, a1;
        const float* Ap = Av + (size_t)a_row * K + k0 + scol;
        f32x4 x0 = {0,0,0,0}, x1 = {0,0,0,0}, x2 = {0,0,0,0}, x3 = {0,0,0,0};
        if (a_ok) {
            x0 = *(const f32x4*)(Ap);
            x1 = *(const f32x4*)(Ap + 4);
            x2 = *(const f32x4*)(Ap + 8);
            x3 = *(const f32x4*)(Ap + 12);
        }
#pragma unroll
        for (int j = 0; j < 4; ++j) {
            a0[j] = (__bf16)x0[j]; a0[4 + j] = (__bf16)x1[j];
            a1[j] = (__bf16)x2[j]; a1[4 + j] = (__bf16)x3[j];
        }
        bf16x8 b0 = *(const bf16x8*)(Bp + k0);
        bf16x8 b1 = *(const bf16x8*)(Bp + k0 + 8);

        __syncthreads();
        *(bf16x8*)&As[srow * LDSTRIDE + scol]     = a0;
        *(bf16x8*)&As[srow * LDSTRIDE + scol + 8] = a1;
        *(bf16x8*)&Bs[srow * LDSTRIDE + scol]     = b0;
        *(bf16x8*)&Bs[srow * LDSTRIDE + scol + 8] = b1;
        __syncthreads();

        bf16x8 af[4], bfr[4];
#pragma unroll
        for (int mt = 0; mt < 4; ++mt)
            af[mt] = *(const bf16x8*)&As[(wm * 64 + mt * 16 + l16) * LDSTRIDE + quad * 8];
#pragma unroll
        for (int nt = 0; nt < 4; ++nt)
            bfr[nt] = *(const bf16x8*)&Bs[(wn * 64 + nt * 16 + l16) * LDSTRIDE + quad * 8];

#pragma unroll
        for (int mt = 0; mt < 4; ++mt)
#pragma unroll
            for (int nt = 0; nt < 4; ++nt)
                acc[mt][nt] = __builtin_amdgcn_mfma_f32_16x16x32_bf16(
                    af[mt], bfr[nt], acc[mt][nt], 0, 0, 0);
    }

#pragma unroll
    for (int nt = 0; nt < 4; ++nt) {
        const int col = col0 + wn * 64 + nt * 16 + l16;
        const float b = bias[col];
#pragma unroll
        for (int mt = 0; mt < 4; ++mt) {
#pragma unroll
            for (int r = 0; r < 4; ++r) {
                const int row = row0 + wm * 64 + mt * 16 + quad * 4 + r;
                if (row < M) {
                    float v = fmaxf(acc[mt][nt][r] + b, 0.f);
                    Cv[(size_t)row * Nc + col] = v;
                }
            }
        }
    }
}

// ------------------- fused MLP: out = relu(A@W1+b1)@W2+b2 + BN stats -------
// M-tile = 128 rows/block, 512 threads (8 waves), 1 block/CU (96KB LDS).
// A 128x256 swz; hid 128x128 swz; 4 chunks of 128 hid cols, fully unrolled.
// pass1 SWAPPED: acc1[mt] = mfma(W1f, af) -> thread holds hid[mt*16+l16]
// [wid*16+quad*4 .. +4] -> bf16x4 vector hid writes.
// pass2: wave owns 32 out cols (acc2[8][2]). W2(c) issued before pass1(c);
// W1(c+1) issued before pass2(c).

__global__ __launch_bounds__(512, 2)
void fused_mlp_kernel(const __bf16* __restrict__ aggb,
                      const __bf16* __restrict__ W1T, const float* __restrict__ b1,
                      const __bf16* __restrict__ W2T, const float* __restrict__ b2,
                      float* __restrict__ out, float* __restrict__ sums, int M)
{
    __shared__ __bf16 As[128 * 256];    // 65536 B, swizzled
    __shared__ __bf16 hidS[128 * 128];  // 32768 B, swizzled

    const int tid  = threadIdx.x;
    const int wid  = tid >> 6;   // 0..7
    const int lane = tid & 63;
    const int quad = lane >> 4;
    const int l16  = lane & 15;
    const int row0 = blockIdx.x * 128;

    // ---- stage A tile (128 x 256 bf16) into LDS, swizzled ----
    {
        const int srow = tid >> 2;        // 0..127
        const int gb8  = (tid & 3) * 8;   // first 8-col group (0,8,16,24)
        const int m = row0 + srow;
        bf16x8 v[8];
        if (m < M) {
            const __bf16* Ap = aggb + (size_t)m * 256 + gb8 * 8;
#pragma unroll
            for (int j = 0; j < 8; ++j) v[j] = *(const bf16x8*)(Ap + j * 8);
        } else {
#pragma unroll
            for (int j = 0; j < 8; ++j)
#pragma unroll
                for (int q = 0; q < 8; ++q) v[j][q] = (__bf16)0.f;
        }
#pragma unroll
        for (int j = 0; j < 8; ++j) {
            const int sg = (gb8 + j) ^ (srow & 7);
            *(bf16x8*)&As[srow * 256 + sg * 8] = v[j];
        }
    }

    f32x4 acc2[8][2];
#pragma unroll
    for (int mt = 0; mt < 8; ++mt)
#pragma unroll
        for (int nt = 0; nt < 2; ++nt) acc2[mt][nt] = (f32x4){0.f, 0.f, 0.f, 0.f};

    // pass1 cols: c*128 + wid*16 (l16 indexes W1 col within wave's 16)
    // pass2 out cols: wid*32 + nt*16 + l16
    const __bf16* W1p = W1T + (size_t)(wid * 16 + l16) * 256 + quad * 8;
    const __bf16* W2p = W2T + (size_t)(wid * 32 + l16) * 512 + quad * 8;

    // prologue: prefetch W1 chunk 0
    bf16x8 w1f[2][8];
#pragma unroll
    for (int kk = 0; kk < 8; ++kk)
        w1f[0][kk] = *(const bf16x8*)(W1p + (size_t)0 + kk * 32);

    __syncthreads();  // A visible

#pragma unroll
    for (int c = 0; c < 4; ++c) {
        const int cur = c & 1;   // static after full unroll
        const int nxt = cur ^ 1;

        // ---- issue W2 loads for this chunk (consumed in pass2 below) ----
        bf16x8 w2f[4][2];
#pragma unroll
        for (int kkl = 0; kkl < 4; ++kkl)
#pragma unroll
            for (int nt = 0; nt < 2; ++nt)
                w2f[kkl][nt] = *(const bf16x8*)(W2p + (size_t)(nt * 16) * 512
                                                + c * 128 + kkl * 32);

        // ---- pass1(c) SWAPPED: acc1[mt] = W1f (A-op) x af (B-op) ----
        // thread result: hid[row = mt*16+l16][col = wid*16+quad*4+r]
        f32x4 acc1[8];
#pragma unroll
        for (int mt = 0; mt < 8; ++mt) acc1[mt] = (f32x4){0.f, 0.f, 0.f, 0.f};
#pragma unroll
        for (int kk = 0; kk < 8; ++kk) {
            const int sg = (kk * 4 + quad) ^ (l16 & 7);
#pragma unroll
            for (int mt = 0; mt < 8; ++mt) {
                bf16x8 af = *(const bf16x8*)&As[(mt * 16 + l16) * 256 + sg * 8];
                acc1[mt] = __builtin_amdgcn_mfma_f32_16x16x32_bf16(
                    w1f[cur][kk], af, acc1[mt], 0, 0, 0);
            }
        }

        __syncthreads();  // pass2(c-1) readers done with hidS

        // ---- write hid(c): row=mt*16+l16, 4 cols at wid*16+quad*4 ----
        {
            const int colb = wid * 16 + quad * 4;
            const f32x4 bb4 = *(const f32x4*)(b1 + c * 128 + colb);
            const int cg = colb >> 3;          // = wid*2 + (quad>>1)
            const int o8 = (quad & 1) * 4;     // elem offset within 8-group
#pragma unroll
            for (int mt = 0; mt < 8; ++mt) {
                const int row = mt * 16 + l16;
                bf16x4 o;
#pragma unroll
                for (int r = 0; r < 4; ++r)
                    o[r] = (__bf16)fmaxf(acc1[mt][r] + bb4[r], 0.f);
                *(bf16x4*)&hidS[row * 128 + ((cg ^ (row & 7)) << 3) + o8] = o;
            }
        }
        __syncthreads();  // hid(c) visible

        // ---- prefetch W1 for chunk c+1 (hidden under pass2) ----
        if (c < 3) {
#pragma unroll
            for (int kk = 0; kk < 8; ++kk)
                w1f[nxt][kk] = *(const bf16x8*)(W1p + (size_t)((c + 1) * 128) * 256
                                                + kk * 32);
        }

        // ---- pass2(c): acc2 += hid(c) @ W2[c*128 .. +128, :] ----
#pragma unroll
        for (int kkl = 0; kkl < 4; ++kkl) {
#pragma unroll
            for (int mt = 0; mt < 8; ++mt) {
                const int sg = (kkl * 4 + quad) ^ (l16 & 7);
                bf16x8 hf = *(const bf16x8*)&hidS[(mt * 16 + l16) * 128 + sg * 8];
#pragma unroll
                for (int nt = 0; nt < 2; ++nt)
                    acc2[mt][nt] = __builtin_amdgcn_mfma_f32_16x16x32_bf16(
                        hf, w2f[kkl][nt], acc2[mt][nt], 0, 0, 0);
            }
        }
    }

    // ---- epilogue: bias + store fp32 + BN stats (8-way replicated) ----
    float* srep = sums + (blockIdx.x & 7) * 512;
#pragma unroll
    for (int nt = 0; nt < 2; ++nt) {
        const int col = wid * 32 + nt * 16 + l16;
        const float bb = b2[col];
        float s = 0.f, ss = 0.f;
#pragma unroll
        for (int mt = 0; mt < 8; ++mt) {
#pragma unroll
            for (int r = 0; r < 4; ++r) {
                const int row = row0 + mt * 16 + quad * 4 + r;
                if (row < M) {
                    float v = acc2[mt][nt][r] + bb;
                    out[(size_t)row * 256 + col] = v;
                    s += v; ss += v * v;
                }
            }
        }
        s += __shfl_xor(s, 16); ss += __shfl_xor(ss, 16);
        s += __shfl_xor(s, 32); ss += __shfl_xor(ss, 32);
        if (lane < 16) {
            atomicAdd(&srep[col], s);
            atomicAdd(&srep[256 + col], ss);
        }
    }
}

// WT[l][n][k] = (bf16) W[l][k][n]
__global__ void convert_wt_kernel(const float* __restrict__ W, __bf16* __restrict__ WT,
                                  int K, int Nc, int total)
{
    int i = blockIdx.x * 256 + threadIdx.x;
    if (i >= total) return;
    int kn = K * Nc;
    int l = i / kn;
    int rem = i - l * kn;
    int n = rem / K;
    int k = rem - n * K;
    WT[i] = (__bf16)W[(size_t)l * kn + (size_t)k * Nc + n];
}

// ------------------------ edge sort (once per launch) ----------------------

__global__ void zero_counts_kernel(int* __restrict__ counts, int N)
{
    int i = blockIdx.x * 256 + threadIdx.x;
    if (i < N) counts[i] = 0;
}

__global__ void hist_kernel(const int* __restrict__ ei, int* __restrict__ counts, int E)
{
    int e = blockIdx.x * 256 + threadIdx.x;
    if (e < E) atomicAdd(&counts[ei[E + e]], 1);
}

__global__ void scan1_kernel(const int* __restrict__ counts, int* __restrict__ partial,
                             int* __restrict__ blocksums, int N)
{
    __shared__ int sm[256];
    int i = blockIdx.x * 256 + threadIdx.x;
    int v = (i < N) ? counts[i] : 0;
    sm[threadIdx.x] = v;
    __syncthreads();
    for (int off = 1; off < 256; off <<= 1) {
        int t = 0;
        if ((int)threadIdx.x >= off) t = sm[threadIdx.x - off];
        __syncthreads();
        if ((int)threadIdx.x >= off) sm[threadIdx.x] += t;
        __syncthreads();
    }
    if (i < N) partial[i] = sm[threadIdx.x] - v;
    if (threadIdx.x == 255) blocksums[blockIdx.x] = sm[255];
}

__global__ void scan2_kernel(int* __restrict__ blocksums, int NB)
{
    __shared__ int sm[1024];
    int v = ((int)threadIdx.x < NB) ? blocksums[threadIdx.x] : 0;
    sm[threadIdx.x] = v;
    __syncthreads();
    for (int off = 1; off < 1024; off <<= 1) {
        int t = 0;
        if ((int)threadIdx.x >= off) t = sm[threadIdx.x - off];
        __syncthreads();
        if ((int)threadIdx.x >= off) sm[threadIdx.x] += t;
        __syncthreads();
    }
    if ((int)threadIdx.x < NB) blocksums[threadIdx.x] = sm[threadIdx.x] - v;
}

__global__ void scan3_kernel(const int* __restrict__ partial, const int* __restrict__ blocksums,
                             int* __restrict__ rowptr, int* __restrict__ woff, int N, int E)
{
    int i = blockIdx.x * 256 + threadIdx.x;
    if (i < N) {
        int v = partial[i] + blocksums[blockIdx.x];
        rowptr[i] = v;
        woff[i] = v;
    }
    if (i == 0) rowptr[N] = E;
}

__global__ void scatter_sort_kernel(const int* __restrict__ ei, const int* __restrict__ ea,
                                    int* __restrict__ woff, int* __restrict__ sorted, int E)
{
    int e = blockIdx.x * 256 + threadIdx.x;
    if (e >= E) return;
    int dst = ei[E + e];
    int src = ei[e];
    int c = ea[2 * e] * 3 + ea[2 * e + 1];
    int pos = atomicAdd(&woff[dst], 1);
    sorted[pos] = (src << 4) | c;
}

// ------------------------ per-layer kernels --------------------------------

__global__ void build_table_kernel(const float* __restrict__ E1, const float* __restrict__ E2,
                                   int l, float* __restrict__ tab, float* __restrict__ selfemb,
                                   float* __restrict__ sums)
{
    int b = blockIdx.x;
    int t = threadIdx.x;
    const float* e1 = E1 + (size_t)l * 6 * 256;
    const float* e2 = E2 + (size_t)l * 3 * 256;
    if (b < 9) {
        tab[b * 256 + t] = e1[(b / 3) * 256 + t] + e2[(b % 3) * 256 + t];
    } else {
        selfemb[t] = e1[4 * 256 + t] + e2[0 * 256 + t];
#pragma unroll
        for (int r = 0; r < 16; ++r) sums[r * 256 + t] = 0.f;  // 8 replicas x 512
    }
}

// aggb[n] = bf16( bn(out[n]) + selfemb + sum_e (bn(out[src_e]) + tab[c_e]) )
// Edge loop unrolled x4: 4 sorted[] + 4 row loads in flight.
template<int APPLY_BN>
__global__ __launch_bounds__(256)
void gather_kernel(const float* __restrict__ out, const int* __restrict__ rowptr,
                   const int* __restrict__ sorted, const float* __restrict__ tab,
                   const float* __restrict__ selfemb, const float* __restrict__ scsh,
                   __bf16* __restrict__ aggb, int N)
{
    int n = blockIdx.x * 4 + (threadIdx.x >> 6);
    if (n >= N) return;
    int lane = threadIdx.x & 63;
    int f = lane * 4;

    f32x4 sc, sh;
    if (APPLY_BN) {
        sc = *(const f32x4*)(scsh + f);
        sh = *(const f32x4*)(scsh + 256 + f);
    }

    int r0 = rowptr[n];
    int r1 = rowptr[n + 1];

    f32x4 hv = *(const f32x4*)(out + (size_t)n * 256 + f);
    if (APPLY_BN) hv = hv * sc + sh;
    f32x4 acc = hv + *(const f32x4*)(selfemb + f);

    int e = r0;
#pragma unroll 1
    for (; e + 4 <= r1; e += 4) {
        int v0 = sorted[e + 0];
        int v1 = sorted[e + 1];
        int v2 = sorted[e + 2];
        int v3 = sorted[e + 3];
        f32x4 x0 = *(const f32x4*)(out + (size_t)(v0 >> 4) * 256 + f);
        f32x4 x1 = *(const f32x4*)(out + (size_t)(v1 >> 4) * 256 + f);
        f32x4 x2 = *(const f32x4*)(out + (size_t)(v2 >> 4) * 256 + f);
        f32x4 x3 = *(const f32x4*)(out + (size_t)(v3 >> 4) * 256 + f);
        f32x4 t0 = *(const f32x4*)(tab + (v0 & 15) * 256 + f);
        f32x4 t1 = *(const f32x4*)(tab + (v1 & 15) * 256 + f);
        f32x4 t2 = *(const f32x4*)(tab + (v2 & 15) * 256 + f);
        f32x4 t3 = *(const f32x4*)(tab + (v3 & 15) * 256 + f);
        if (APPLY_BN) {
            x0 = x0 * sc + sh; x1 = x1 * sc + sh;
            x2 = x2 * sc + sh; x3 = x3 * sc + sh;
        }
        acc += (x0 + t0) + (x1 + t1);
        acc += (x2 + t2) + (x3 + t3);
    }
#pragma unroll 1
    for (; e < r1; ++e) {
        int v = sorted[e];
        f32x4 xv = *(const f32x4*)(out + (size_t)(v >> 4) * 256 + f);
        if (APPLY_BN) xv = xv * sc + sh;
        acc += xv + *(const f32x4*)(tab + (v & 15) * 256 + f);
    }
    bf16x4 o;
#pragma unroll
    for (int j = 0; j < 4; ++j) o[j] = (__bf16)acc[j];
    *(bf16x4*)(aggb + (size_t)n * 256 + f) = o;
}

__global__ void bn_finalize_kernel(const float* __restrict__ sums,
                                   const float* __restrict__ gamma,
                                   const float* __restrict__ beta,
                                   int l, int M, float* __restrict__ scsh)
{
    int c = threadIdx.x;  // 256
    float s = 0.f, ss = 0.f;
#pragma unroll
    for (int r = 0; r < 8; ++r) {
        s  += sums[r * 512 + c];
        ss += sums[r * 512 + 256 + c];
    }
    float inv = 1.f / (float)M;
    float mean = s * inv;
    float var = ss * inv - mean * mean;
    float sc = gamma[l * 256 + c] * rsqrtf(var + 1e-5f);
    scsh[c] = sc;
    scsh[256 + c] = beta[l * 256 + c] - mean * sc;
}

// h = out * scale + shift  (final layer only)
__global__ __launch_bounds__(256)
void bn_apply_kernel(const float* __restrict__ out, const float* __restrict__ scsh,
                     float* __restrict__ h, int total4)
{
    int i = blockIdx.x * 256 + threadIdx.x;
    if (i >= total4) return;
    int cg = i & 63;
    f32x4 sc = ((const f32x4*)scsh)[cg];
    f32x4 sh = ((const f32x4*)scsh)[64 + cg];
    f32x4 v = ((const f32x4*)out)[i];
    ((f32x4*)h)[i] = v * sc + sh;
}

extern "C" void kernel_launch(void* const* d_in, const int* in_sizes, int n_in,
                              void* d_out, int out_size, void* d_ws, size_t ws_size,
                              hipStream_t stream)
{
    const float* x     = (const float*)d_in[0];
    const int*   ei    = (const int*)d_in[1];
    const int*   ea    = (const int*)d_in[2];
    const float* Wl    = (const float*)d_in[3];
    const float* bl    = (const float*)d_in[4];
    const float* W1    = (const float*)d_in[5];
    const float* b1    = (const float*)d_in[6];
    const float* W2    = (const float*)d_in[7];
    const float* b2    = (const float*)d_in[8];
    const float* E1    = (const float*)d_in[9];
    const float* E2    = (const float*)d_in[10];
    const float* gamma = (const float*)d_in[11];
    const float* beta  = (const float*)d_in[12];

    const int N = in_sizes[0] / 128;
    const int E = in_sizes[1] / 2;

    // d_out space doubles as the bf16 agg buffer; final bn_apply overwrites it.
    __bf16* aggb = (__bf16*)d_out;               // N x 256 bf16
    float*  hfin = (float*)d_out;                // final output view

    // workspace layout
    float*  out  = (float*)d_ws;                     // N x 256 fp32
    __bf16* WlT  = (__bf16*)(out + (size_t)N * 256); // 256 x 128
    __bf16* W1T  = WlT + 256 * 128;                  // 5 x 512 x 256
    __bf16* W2T  = W1T + 5 * 512 * 256;              // 5 x 256 x 512
    float*  tab  = (float*)(W2T + 5 * 256 * 512);    // 9 x 256
    float*  selfemb = tab + 9 * 256;                 // 256
    float*  sums = selfemb + 256;                    // 8 replicas x 512 = 4096
    float*  scsh = sums + 4096;                      // 512
    int*    counts = (int*)(scsh + 512);             // N
    int*    partial = counts + N;                    // N
    int*    rowptr  = partial + N;                   // N+1
    int*    woff    = rowptr + N + 1;                // N
    int*    sorted  = woff + N;                      // E
    int*    blocksums = sorted + E;                  // <=1024

    const int NB = (N + 255) / 256;
    const int EB = (E + 255) / 256;

    // --- edge sort by dst (edges constant across layers) ---
    zero_counts_kernel<<<NB, 256, 0, stream>>>(counts, N);
    hist_kernel<<<EB, 256, 0, stream>>>(ei, counts, E);
    scan1_kernel<<<NB, 256, 0, stream>>>(counts, partial, blocksums, N);
    scan2_kernel<<<1, 1024, 0, stream>>>(blocksums, NB);
    scan3_kernel<<<NB, 256, 0, stream>>>(partial, blocksums, rowptr, woff, N, E);
    scatter_sort_kernel<<<EB, 256, 0, stream>>>(ei, ea, woff, sorted, E);

    // --- weight conversion (transposed bf16) ---
    convert_wt_kernel<<<(128 * 256 + 255) / 256, 256, 0, stream>>>(Wl, WlT, 128, 256, 128 * 256);
    convert_wt_kernel<<<(5 * 256 * 512 + 255) / 256, 256, 0, stream>>>(W1, W1T, 256, 512, 5 * 256 * 512);
    convert_wt_kernel<<<(5 * 512 * 256 + 255) / 256, 256, 0, stream>>>(W2, W2T, 512, 256, 5 * 512 * 256);

    const int mtiles128 = (N + 127) / 128;
    const int total4 = N * 64;
    const int ew_blocks = (total4 + 255) / 256;
    const int gb = (N + 3) / 4;

    // out = relu(x @ Wl + bl)
    gemm0_kernel<<<dim3(2, mtiles128), 256, 0, stream>>>(x, WlT, bl, out, N, 128, 256);

    for (int l = 0; l < 5; ++l) {
        build_table_kernel<<<10, 256, 0, stream>>>(E1, E2, l, tab, selfemb, sums);
        if (l == 0)
            gather_kernel<0><<<gb, 256, 0, stream>>>(out, rowptr, sorted, tab, selfemb,
                                                     scsh, aggb, N);
        else
            gather_kernel<1><<<gb, 256, 0, stream>>>(out, rowptr, sorted, tab, selfemb,
                                                     scsh, aggb, N);
        fused_mlp_kernel<<<mtiles128, 512, 0, stream>>>(
            aggb, W1T + (size_t)l * 512 * 256, b1 + l * 512,
            W2T + (size_t)l * 256 * 512, b2 + l * 256, out, sums, N);
        bn_finalize_kernel<<<1, 256, 0, stream>>>(sums, gamma, beta, l, N, scsh);
    }
    // final h = bn(out) -> d_out (fp32)
    bn_apply_kernel<<<ew_blocks, 256, 0, stream>>>(out, scsh, hfin, total4);
}

// Round 9
// 1230.583 us; speedup vs baseline: 1.1223x; 1.1223x over previous
//
#include <hip/hip_runtime.h>
#include <hip/hip_bf16.h>

// ---------------------------------------------------------------------------
// GNN pretrain forward: h=relu(x@Wl+bl); 5x [gather-agg -> fusedMLP -> BN]
// R13: byte-diet round. R12's operand swap reverted (conflicts rose, -3us).
//   - bf16 mirror outb (2nd half of d_out): gemm0 + mlp layers 0-3 write ONLY
//     outb (fp32 out was dead: gather re-quantizes to bf16 anyway). Layer 4
//     writes ONLY fp32 out (feeds bn_apply).
//   - gather reads bf16 rows: 500->250MB/layer random reads, working set
//     100->50MB (better L2/L3 fit). Gather was ~88us/layer at ~5.7TB/s
//     effective = byte-bound; halving bytes ~halves it.
//   - fused_mlp core = R11 (147us proven): M=128 tile, 512thr, 96KB LDS.
// ---------------------------------------------------------------------------

typedef __bf16 bf16x8 __attribute__((ext_vector_type(8)));
typedef __bf16 bf16x4 __attribute__((ext_vector_type(4)));
typedef float f32x4 __attribute__((ext_vector_type(4)));

#define LDSTRIDE 40  // gemm0 LDS pad

// ------------------- gemm0 (fp32 in, bf16 out, relu) -----------------------
// 128x128 block tile, 4 waves (2x2), each wave 64x64 = 4x4 MFMA tiles.
__global__ __launch_bounds__(256, 2)
void gemm0_kernel(const float* __restrict__ Av, const __bf16* __restrict__ BT,
                  const float* __restrict__ bias, __bf16* __restrict__ Cb,
                  int M, int K, int Nc)
{
    __shared__ __bf16 As[128 * LDSTRIDE];
    __shared__ __bf16 Bs[128 * LDSTRIDE];

    const int tid  = threadIdx.x;
    const int wave = tid >> 6;
    const int lane = tid & 63;
    const int quad = lane >> 4;
    const int l16  = lane & 15;
    const int wm   = wave >> 1;
    const int wn   = wave & 1;

    const int col0 = blockIdx.x * 128;
    const int row0 = blockIdx.y * 128;

    f32x4 acc[4][4];
#pragma unroll
    for (int mt = 0; mt < 4; ++mt)
#pragma unroll
        for (int nt = 0; nt < 4; ++nt) acc[mt][nt] = (f32x4){0.f, 0.f, 0.f, 0.f};

    const int srow = tid >> 1;
    const int scol = (tid & 1) * 16;
    const int a_row = row0 + srow;
    const bool a_ok = (a_row < M);
    const __bf16* Bp = BT + (size_t)(col0 + srow) * K + scol;

    for (int k0 = 0; k0 < K; k0 += 32) {
        bf16x8 a0, a1;
        const float* Ap = Av + (size_t)a_row * K + k0 + scol;
        f32x4 x0 = {0,0,0,0}, x1 = {0,0,0,0}, x2 = {0,0,0,0}, x3 = {0,0,0,0};
        if (a_ok) {
            x0 = *(const f32x4*)(Ap);
            x1 = *(const f32x4*)(Ap + 4);
            x2 = *(const f32x4*)(Ap + 8);
            x3 = *(const f32x4*)(Ap + 12);
        }
#pragma unroll
        for (int j = 0; j < 4; ++j) {
            a0[j] = (__bf16)x0[j]; a0[4 + j] = (__bf16)x1[j];
            a1[j] = (__bf16)x2[j]; a1[4 + j] = (__bf16)x3[j];
        }
        bf16x8 b0 = *(const bf16x8*)(Bp + k0);
        bf16x8 b1 = *(const bf16x8*)(Bp + k0 + 8);

        __syncthreads();
        *(bf16x8*)&As[srow * LDSTRIDE + scol]     = a0;
        *(bf16x8*)&As[srow * LDSTRIDE + scol + 8] = a1;
        *(bf16x8*)&Bs[srow * LDSTRIDE + scol]     = b0;
        *(bf16x8*)&Bs[srow * LDSTRIDE + scol + 8] = b1;
        __syncthreads();

        bf16x8 af[4], bfr[4];
#pragma unroll
        for (int mt = 0; mt < 4; ++mt)
            af[mt] = *(const bf16x8*)&As[(wm * 64 + mt * 16 + l16) * LDSTRIDE + quad * 8];
#pragma unroll
        for (int nt = 0; nt < 4; ++nt)
            bfr[nt] = *(const bf16x8*)&Bs[(wn * 64 + nt * 16 + l16) * LDSTRIDE + quad * 8];

#pragma unroll
        for (int mt = 0; mt < 4; ++mt)
#pragma unroll
            for (int nt = 0; nt < 4; ++nt)
                acc[mt][nt] = __builtin_amdgcn_mfma_f32_16x16x32_bf16(
                    af[mt], bfr[nt], acc[mt][nt], 0, 0, 0);
    }

#pragma unroll
    for (int nt = 0; nt < 4; ++nt) {
        const int col = col0 + wn * 64 + nt * 16 + l16;
        const float b = bias[col];
#pragma unroll
        for (int mt = 0; mt < 4; ++mt) {
#pragma unroll
            for (int r = 0; r < 4; ++r) {
                const int row = row0 + wm * 64 + mt * 16 + quad * 4 + r;
                if (row < M) {
                    float v = fmaxf(acc[mt][nt][r] + b, 0.f);
                    Cb[(size_t)row * Nc + col] = (__bf16)v;
                }
            }
        }
    }
}

// ------------------- fused MLP: out = relu(A@W1+b1)@W2+b2 + BN stats -------
// M-tile = 128 rows/block, 512 threads (8 waves), 1 block/CU (96KB LDS).
// A 128x256 swz; hid 128x128 swz; 4 chunks of 128 hid cols, fully unrolled.
// FINAL=0: store bf16 to outb. FINAL=1: store fp32 to outf (layer 4 only).

template<int FINAL>
__global__ __launch_bounds__(512, 2)
void fused_mlp_kernel(const __bf16* __restrict__ aggb,
                      const __bf16* __restrict__ W1T, const float* __restrict__ b1,
                      const __bf16* __restrict__ W2T, const float* __restrict__ b2,
                      float* __restrict__ outf, __bf16* __restrict__ outb,
                      float* __restrict__ sums, int M)
{
    __shared__ __bf16 As[128 * 256];    // 65536 B, swizzled
    __shared__ __bf16 hidS[128 * 128];  // 32768 B, swizzled

    const int tid  = threadIdx.x;
    const int wid  = tid >> 6;   // 0..7
    const int lane = tid & 63;
    const int quad = lane >> 4;
    const int l16  = lane & 15;
    const int row0 = blockIdx.x * 128;

    // ---- stage A tile (128 x 256 bf16) into LDS, swizzled ----
    {
        const int srow = tid >> 2;        // 0..127
        const int gb8  = (tid & 3) * 8;   // first 8-col group (0,8,16,24)
        const int m = row0 + srow;
        bf16x8 v[8];
        if (m < M) {
            const __bf16* Ap = aggb + (size_t)m * 256 + gb8 * 8;
#pragma unroll
            for (int j = 0; j < 8; ++j) v[j] = *(const bf16x8*)(Ap + j * 8);
        } else {
#pragma unroll
            for (int j = 0; j < 8; ++j)
#pragma unroll
                for (int q = 0; q < 8; ++q) v[j][q] = (__bf16)0.f;
        }
#pragma unroll
        for (int j = 0; j < 8; ++j) {
            const int sg = (gb8 + j) ^ (srow & 7);
            *(bf16x8*)&As[srow * 256 + sg * 8] = v[j];
        }
    }

    f32x4 acc2[8][2];
#pragma unroll
    for (int mt = 0; mt < 8; ++mt)
#pragma unroll
        for (int nt = 0; nt < 2; ++nt) acc2[mt][nt] = (f32x4){0.f, 0.f, 0.f, 0.f};

    // pass1 cols: c*128 + wid*16 + l16 ; pass2 out cols: wid*32 + nt*16 + l16
    const __bf16* W1p = W1T + (size_t)(wid * 16 + l16) * 256 + quad * 8;
    const __bf16* W2p = W2T + (size_t)(wid * 32 + l16) * 512 + quad * 8;

    // prologue: prefetch W1 chunk 0
    bf16x8 w1f[2][8];
#pragma unroll
    for (int kk = 0; kk < 8; ++kk)
        w1f[0][kk] = *(const bf16x8*)(W1p + (size_t)0 + kk * 32);

    __syncthreads();  // A visible

#pragma unroll
    for (int c = 0; c < 4; ++c) {
        const int cur = c & 1;   // static after full unroll
        const int nxt = cur ^ 1;

        // ---- issue W2 loads for this chunk (consumed in pass2 below) ----
        bf16x8 w2f[4][2];
#pragma unroll
        for (int kkl = 0; kkl < 4; ++kkl)
#pragma unroll
            for (int nt = 0; nt < 2; ++nt)
                w2f[kkl][nt] = *(const bf16x8*)(W2p + (size_t)(nt * 16) * 512
                                                + c * 128 + kkl * 32);

        // ---- pass1(c): acc1 = A @ W1[:, c*128 + wid*16 .. +16) ----
        f32x4 acc1[8];
#pragma unroll
        for (int mt = 0; mt < 8; ++mt) acc1[mt] = (f32x4){0.f, 0.f, 0.f, 0.f};
#pragma unroll
        for (int kk = 0; kk < 8; ++kk) {
            const int sg = (kk * 4 + quad) ^ (l16 & 7);
#pragma unroll
            for (int mt = 0; mt < 8; ++mt) {
                bf16x8 af = *(const bf16x8*)&As[(mt * 16 + l16) * 256 + sg * 8];
                acc1[mt] = __builtin_amdgcn_mfma_f32_16x16x32_bf16(
                    af, w1f[cur][kk], acc1[mt], 0, 0, 0);
            }
        }

        __syncthreads();  // pass2(c-1) readers done with hidS

        // ---- write hid(c): col = wid*16 + l16, swizzled ----
        {
            const int lcol = wid * 16 + l16;
            const float bb = b1[c * 128 + lcol];
            const int cg = lcol >> 3;
            const int c7 = lcol & 7;
#pragma unroll
            for (int mt = 0; mt < 8; ++mt)
#pragma unroll
                for (int r = 0; r < 4; ++r) {
                    const int row = mt * 16 + quad * 4 + r;
                    float v = fmaxf(acc1[mt][r] + bb, 0.f);
                    hidS[row * 128 + ((cg ^ (row & 7)) << 3) + c7] = (__bf16)v;
                }
        }
        __syncthreads();  // hid(c) visible

        // ---- prefetch W1 for chunk c+1 (hidden under pass2) ----
        if (c < 3) {
#pragma unroll
            for (int kk = 0; kk < 8; ++kk)
                w1f[nxt][kk] = *(const bf16x8*)(W1p + (size_t)((c + 1) * 128) * 256
                                                + kk * 32);
        }

        // ---- pass2(c): acc2 += hid(c) @ W2[c*128 .. +128, :] ----
#pragma unroll
        for (int kkl = 0; kkl < 4; ++kkl) {
#pragma unroll
            for (int mt = 0; mt < 8; ++mt) {
                const int sg = (kkl * 4 + quad) ^ (l16 & 7);
                bf16x8 hf = *(const bf16x8*)&hidS[(mt * 16 + l16) * 128 + sg * 8];
#pragma unroll
                for (int nt = 0; nt < 2; ++nt)
                    acc2[mt][nt] = __builtin_amdgcn_mfma_f32_16x16x32_bf16(
                        hf, w2f[kkl][nt], acc2[mt][nt], 0, 0, 0);
            }
        }
    }

    // ---- epilogue: bias + store (bf16 or fp32) + BN stats (8-way repl) ----
    float* srep = sums + (blockIdx.x & 7) * 512;
#pragma unroll
    for (int nt = 0; nt < 2; ++nt) {
        const int col = wid * 32 + nt * 16 + l16;
        const float bb = b2[col];
        float s = 0.f, ss = 0.f;
#pragma unroll
        for (int mt = 0; mt < 8; ++mt) {
#pragma unroll
            for (int r = 0; r < 4; ++r) {
                const int row = row0 + mt * 16 + quad * 4 + r;
                if (row < M) {
                    float v = acc2[mt][nt][r] + bb;
                    if (FINAL)
                        outf[(size_t)row * 256 + col] = v;
                    else
                        outb[(size_t)row * 256 + col] = (__bf16)v;
                    s += v; ss += v * v;
                }
            }
        }
        s += __shfl_xor(s, 16); ss += __shfl_xor(ss, 16);
        s += __shfl_xor(s, 32); ss += __shfl_xor(ss, 32);
        if (lane < 16) {
            atomicAdd(&srep[col], s);
            atomicAdd(&srep[256 + col], ss);
        }
    }
}

// WT[l][n][k] = (bf16) W[l][k][n]
__global__ void convert_wt_kernel(const float* __restrict__ W, __bf16* __restrict__ WT,
                                  int K, int Nc, int total)
{
    int i = blockIdx.x * 256 + threadIdx.x;
    if (i >= total) return;
    int kn = K * Nc;
    int l = i / kn;
    int rem = i - l * kn;
    int n = rem / K;
    int k = rem - n * K;
    WT[i] = (__bf16)W[(size_t)l * kn + (size_t)k * Nc + n];
}

// ------------------------ edge sort (once per launch) ----------------------

__global__ void zero_counts_kernel(int* __restrict__ counts, int N)
{
    int i = blockIdx.x * 256 + threadIdx.x;
    if (i < N) counts[i] = 0;
}

__global__ void hist_kernel(const int* __restrict__ ei, int* __restrict__ counts, int E)
{
    int e = blockIdx.x * 256 + threadIdx.x;
    if (e < E) atomicAdd(&counts[ei[E + e]], 1);
}

__global__ void scan1_kernel(const int* __restrict__ counts, int* __restrict__ partial,
                             int* __restrict__ blocksums, int N)
{
    __shared__ int sm[256];
    int i = blockIdx.x * 256 + threadIdx.x;
    int v = (i < N) ? counts[i] : 0;
    sm[threadIdx.x] = v;
    __syncthreads();
    for (int off = 1; off < 256; off <<= 1) {
        int t = 0;
        if ((int)threadIdx.x >= off) t = sm[threadIdx.x - off];
        __syncthreads();
        if ((int)threadIdx.x >= off) sm[threadIdx.x] += t;
        __syncthreads();
    }
    if (i < N) partial[i] = sm[threadIdx.x] - v;
    if (threadIdx.x == 255) blocksums[blockIdx.x] = sm[255];
}

__global__ void scan2_kernel(int* __restrict__ blocksums, int NB)
{
    __shared__ int sm[1024];
    int v = ((int)threadIdx.x < NB) ? blocksums[threadIdx.x] : 0;
    sm[threadIdx.x] = v;
    __syncthreads();
    for (int off = 1; off < 1024; off <<= 1) {
        int t = 0;
        if ((int)threadIdx.x >= off) t = sm[threadIdx.x - off];
        __syncthreads();
        if ((int)threadIdx.x >= off) sm[threadIdx.x] += t;
        __syncthreads();
    }
    if ((int)threadIdx.x < NB) blocksums[threadIdx.x] = sm[threadIdx.x] - v;
}

__global__ void scan3_kernel(const int* __restrict__ partial, const int* __restrict__ blocksums,
                             int* __restrict__ rowptr, int* __restrict__ woff, int N, int E)
{
    int i = blockIdx.x * 256 + threadIdx.x;
    if (i < N) {
        int v = partial[i] + blocksums[blockIdx.x];
        rowptr[i] = v;
        woff[i] = v;
    }
    if (i == 0) rowptr[N] = E;
}

__global__ void scatter_sort_kernel(const int* __restrict__ ei, const int* __restrict__ ea,
                                    int* __restrict__ woff, int* __restrict__ sorted, int E)
{
    int e = blockIdx.x * 256 + threadIdx.x;
    if (e >= E) return;
    int dst = ei[E + e];
    int src = ei[e];
    int c = ea[2 * e] * 3 + ea[2 * e + 1];
    int pos = atomicAdd(&woff[dst], 1);
    sorted[pos] = (src << 4) | c;
}

// ------------------------ per-layer kernels --------------------------------

__global__ void build_table_kernel(const float* __restrict__ E1, const float* __restrict__ E2,
                                   int l, float* __restrict__ tab, float* __restrict__ selfemb,
                                   float* __restrict__ sums)
{
    int b = blockIdx.x;
    int t = threadIdx.x;
    const float* e1 = E1 + (size_t)l * 6 * 256;
    const float* e2 = E2 + (size_t)l * 3 * 256;
    if (b < 9) {
        tab[b * 256 + t] = e1[(b / 3) * 256 + t] + e2[(b % 3) * 256 + t];
    } else {
        selfemb[t] = e1[4 * 256 + t] + e2[0 * 256 + t];
#pragma unroll
        for (int r = 0; r < 16; ++r) sums[r * 256 + t] = 0.f;  // 8 replicas x 512
    }
}

// aggb[n] = bf16( bn(hb[n]) + selfemb + sum_e (bn(hb[src_e]) + tab[c_e]) )
// hb is the bf16 h-mirror: 8B/lane row reads (was 16B fp32). x4 unrolled.
template<int APPLY_BN>
__global__ __launch_bounds__(256)
void gather_kernel(const __bf16* __restrict__ hb, const int* __restrict__ rowptr,
                   const int* __restrict__ sorted, const float* __restrict__ tab,
                   const float* __restrict__ selfemb, const float* __restrict__ scsh,
                   __bf16* __restrict__ aggb, int N)
{
    int n = blockIdx.x * 4 + (threadIdx.x >> 6);
    if (n >= N) return;
    int lane = threadIdx.x & 63;
    int f = lane * 4;

    f32x4 sc, sh;
    if (APPLY_BN) {
        sc = *(const f32x4*)(scsh + f);
        sh = *(const f32x4*)(scsh + 256 + f);
    }

    int r0 = rowptr[n];
    int r1 = rowptr[n + 1];

    bf16x4 hq = *(const bf16x4*)(hb + (size_t)n * 256 + f);
    f32x4 hv;
#pragma unroll
    for (int j = 0; j < 4; ++j) hv[j] = (float)hq[j];
    if (APPLY_BN) hv = hv * sc + sh;
    f32x4 acc = hv + *(const f32x4*)(selfemb + f);

    int e = r0;
#pragma unroll 1
    for (; e + 4 <= r1; e += 4) {
        int v0 = sorted[e + 0];
        int v1 = sorted[e + 1];
        int v2 = sorted[e + 2];
        int v3 = sorted[e + 3];
        bf16x4 q0 = *(const bf16x4*)(hb + (size_t)(v0 >> 4) * 256 + f);
        bf16x4 q1 = *(const bf16x4*)(hb + (size_t)(v1 >> 4) * 256 + f);
        bf16x4 q2 = *(const bf16x4*)(hb + (size_t)(v2 >> 4) * 256 + f);
        bf16x4 q3 = *(const bf16x4*)(hb + (size_t)(v3 >> 4) * 256 + f);
        f32x4 t0 = *(const f32x4*)(tab + (v0 & 15) * 256 + f);
        f32x4 t1 = *(const f32x4*)(tab + (v1 & 15) * 256 + f);
        f32x4 t2 = *(const f32x4*)(tab + (v2 & 15) * 256 + f);
        f32x4 t3 = *(const f32x4*)(tab + (v3 & 15) * 256 + f);
        f32x4 x0, x1, x2, x3;
#pragma unroll
        for (int j = 0; j < 4; ++j) {
            x0[j] = (float)q0[j]; x1[j] = (float)q1[j];
            x2[j] = (float)q2[j]; x3[j] = (float)q3[j];
        }
        if (APPLY_BN) {
            x0 = x0 * sc + sh; x1 = x1 * sc + sh;
            x2 = x2 * sc + sh; x3 = x3 * sc + sh;
        }
        acc += (x0 + t0) + (x1 + t1);
        acc += (x2 + t2) + (x3 + t3);
    }
#pragma unroll 1
    for (; e < r1; ++e) {
        int v = sorted[e];
        bf16x4 q = *(const bf16x4*)(hb + (size_t)(v >> 4) * 256 + f);
        f32x4 xv;
#pragma unroll
        for (int j = 0; j < 4; ++j) xv[j] = (float)q[j];
        if (APPLY_BN) xv = xv * sc + sh;
        acc += xv + *(const f32x4*)(tab + (v & 15) * 256 + f);
    }
    bf16x4 o;
#pragma unroll
    for (int j = 0; j < 4; ++j) o[j] = (__bf16)acc[j];
    *(bf16x4*)(aggb + (size_t)n * 256 + f) = o;
}

__global__ void bn_finalize_kernel(const float* __restrict__ sums,
                                   const float* __restrict__ gamma,
                                   const float* __restrict__ beta,
                                   int l, int M, float* __restrict__ scsh)
{
    int c = threadIdx.x;  // 256
    float s = 0.f, ss = 0.f;
#pragma unroll
    for (int r = 0; r < 8; ++r) {
        s  += sums[r * 512 + c];
        ss += sums[r * 512 + 256 + c];
    }
    float inv = 1.f / (float)M;
    float mean = s * inv;
    float var = ss * inv - mean * mean;
    float sc = gamma[l * 256 + c] * rsqrtf(var + 1e-5f);
    scsh[c] = sc;
    scsh[256 + c] = beta[l * 256 + c] - mean * sc;
}

// h = out * scale + shift  (final layer only, fp32 in/out)
__global__ __launch_bounds__(256)
void bn_apply_kernel(const float* __restrict__ out, const float* __restrict__ scsh,
                     float* __restrict__ h, int total4)
{
    int i = blockIdx.x * 256 + threadIdx.x;
    if (i >= total4) return;
    int cg = i & 63;
    f32x4 sc = ((const f32x4*)scsh)[cg];
    f32x4 sh = ((const f32x4*)scsh)[64 + cg];
    f32x4 v = ((const f32x4*)out)[i];
    ((f32x4*)h)[i] = v * sc + sh;
}

extern "C" void kernel_launch(void* const* d_in, const int* in_sizes, int n_in,
                              void* d_out, int out_size, void* d_ws, size_t ws_size,
                              hipStream_t stream)
{
    const float* x     = (const float*)d_in[0];
    const int*   ei    = (const int*)d_in[1];
    const int*   ea    = (const int*)d_in[2];
    const float* Wl    = (const float*)d_in[3];
    const float* bl    = (const float*)d_in[4];
    const float* W1    = (const float*)d_in[5];
    const float* b1    = (const float*)d_in[6];
    const float* W2    = (const float*)d_in[7];
    const float* b2    = (const float*)d_in[8];
    const float* E1    = (const float*)d_in[9];
    const float* E2    = (const float*)d_in[10];
    const float* gamma = (const float*)d_in[11];
    const float* beta  = (const float*)d_in[12];

    const int N = in_sizes[0] / 128;
    const int E = in_sizes[1] / 2;

    // d_out (N x 256 fp32 = 2 x 50MB) split: aggb | outb. bn_apply overwrites.
    __bf16* aggb = (__bf16*)d_out;               // N x 256 bf16
    __bf16* outb = aggb + (size_t)N * 256;       // N x 256 bf16 (h mirror)
    float*  hfin = (float*)d_out;                // final output view

    // workspace layout
    float*  out  = (float*)d_ws;                     // N x 256 fp32 (layer 4)
    __bf16* WlT  = (__bf16*)(out + (size_t)N * 256); // 256 x 128
    __bf16* W1T  = WlT + 256 * 128;                  // 5 x 512 x 256
    __bf16* W2T  = W1T + 5 * 512 * 256;              // 5 x 256 x 512
    float*  tab  = (float*)(W2T + 5 * 256 * 512);    // 9 x 256
    float*  selfemb = tab + 9 * 256;                 // 256
    float*  sums = selfemb + 256;                    // 8 replicas x 512 = 4096
    float*  scsh = sums + 4096;                      // 512
    int*    counts = (int*)(scsh + 512);             // N
    int*    partial = counts + N;                    // N
    int*    rowptr  = partial + N;                   // N+1
    int*    woff    = rowptr + N + 1;                // N
    int*    sorted  = woff + N;                      // E
    int*    blocksums = sorted + E;                  // <=1024

    const int NB = (N + 255) / 256;
    const int EB = (E + 255) / 256;

    // --- edge sort by dst (edges constant across layers) ---
    zero_counts_kernel<<<NB, 256, 0, stream>>>(counts, N);
    hist_kernel<<<EB, 256, 0, stream>>>(ei, counts, E);
    scan1_kernel<<<NB, 256, 0, stream>>>(counts, partial, blocksums, N);
    scan2_kernel<<<1, 1024, 0, stream>>>(blocksums, NB);
    scan3_kernel<<<NB, 256, 0, stream>>>(partial, blocksums, rowptr, woff, N, E);
    scatter_sort_kernel<<<EB, 256, 0, stream>>>(ei, ea, woff, sorted, E);

    // --- weight conversion (transposed bf16) ---
    convert_wt_kernel<<<(128 * 256 + 255) / 256, 256, 0, stream>>>(Wl, WlT, 128, 256, 128 * 256);
    convert_wt_kernel<<<(5 * 256 * 512 + 255) / 256, 256, 0, stream>>>(W1, W1T, 256, 512, 5 * 256 * 512);
    convert_wt_kernel<<<(5 * 512 * 256 + 255) / 256, 256, 0, stream>>>(W2, W2T, 512, 256, 5 * 512 * 256);

    const int mtiles128 = (N + 127) / 128;
    const int total4 = N * 64;
    const int ew_blocks = (total4 + 255) / 256;
    const int gb = (N + 3) / 4;

    // h0 = relu(x @ Wl + bl) -> bf16 mirror
    gemm0_kernel<<<dim3(2, mtiles128), 256, 0, stream>>>(x, WlT, bl, outb, N, 128, 256);

    for (int l = 0; l < 5; ++l) {
        build_table_kernel<<<10, 256, 0, stream>>>(E1, E2, l, tab, selfemb, sums);
        if (l == 0)
            gather_kernel<0><<<gb, 256, 0, stream>>>(outb, rowptr, sorted, tab, selfemb,
                                                     scsh, aggb, N);
        else
            gather_kernel<1><<<gb, 256, 0, stream>>>(outb, rowptr, sorted, tab, selfemb,
                                                     scsh, aggb, N);
        if (l < 4)
            fused_mlp_kernel<0><<<mtiles128, 512, 0, stream>>>(
                aggb, W1T + (size_t)l * 512 * 256, b1 + l * 512,
                W2T + (size_t)l * 256 * 512, b2 + l * 256, out, outb, sums, N);
        else
            fused_mlp_kernel<1><<<mtiles128, 512, 0, stream>>>(
                aggb, W1T + (size_t)l * 512 * 256, b1 + l * 512,
                W2T + (size_t)l * 256 * 512, b2 + l * 256, out, outb, sums, N);
        bn_finalize_kernel<<<1, 256, 0, stream>>>(sums, gamma, beta, l, N, scsh);
    }
    // final h = bn(out fp32) -> d_out (overwrites aggb/outb, both dead)
    bn_apply_kernel<<<ew_blocks, 256, 0, stream>>>(out, scsh, hfin, total4);
}